// Round 19
// baseline (2078.726 us; speedup 1.0000x reference)
//
#include <hip/hip_runtime.h>
#include <math.h>

// LSTM persistent kernel, R19: split-K accumulator chains to SPREAD MFMA
// retirements. One block per batch (64 blocks), 512 threads = 8 waves;
// wave wv owns all 4 gates of elements 16wv..16wv+15; in-wave tail; one
// barrier/step; bias as C operand of the first i-chain MFMA.
//
// R13-R18 consolidated: wall(981cy) ~= MFMA busy (518) + VALU busy (514),
// near-zero overlap. Cause: 4-chain c-major interleave clusters every
// chain's FINAL MFMA in the last 4 issue slots -> all gate preacts become
// ready only after the full ~590cy drain; the VALU has nothing to do
// during it. R19 splits each gate's K-sum into two independent 2-deep
// chains (c=0,1 / c=2,3), 8 chains round-robin (8-slot self-spacing ~150cy
// >> MFMA latency, avoiding R16's pipe starvation). Gate i's preact is
// complete ~10/16 through the drain, f at 12/16, g at 14/16 -> ~220cy of
// sigmoid work overlaps the drain. Cost: 2 extra v4f adds/gate + 16 VGPRs.
constexpr int Hdim = 128;
constexpr int TMAX = 4096;

typedef _Float16 v8h __attribute__((ext_vector_type(8)));
typedef float v4f __attribute__((ext_vector_type(4)));

#if __has_builtin(__builtin_amdgcn_exp2f)
__device__ __forceinline__ float exp2_fast(float x) {
  return __builtin_amdgcn_exp2f(x);
}
#else
__device__ __forceinline__ float exp2_fast(float x) {
  return __expf(x * 0.6931471805599453f);
}
#endif

__device__ __forceinline__ float sel4(v4f d, int r) {
  const float s01 = (r & 1) ? d.y : d.x;
  const float s23 = (r & 1) ? d.w : d.z;
  return (r & 2) ? s23 : s01;
}

__global__ __launch_bounds__(512) void lstm_mfma(
    const float* __restrict__ data, const float* __restrict__ h0,
    const float* __restrict__ c0, const float* __restrict__ W_ih,
    const float* __restrict__ W_hh, const float* __restrict__ b_ih,
    const float* __restrict__ b_hh, const float* __restrict__ W_out,
    const float* __restrict__ b_out, float* __restrict__ out, int T) {
  __shared__ __align__(16) float xs[TMAX];
  __shared__ __align__(16) _Float16 hbuf[2][Hdim];

  const int b = blockIdx.x;
  const int tid = threadIdx.x;
  const int lane = tid & 63;
  const int wv = tid >> 6;  // wave 0..7 owns elements 16wv..16wv+15
  const int p = lane >> 4;  // 0..3
  const int m = lane & 15;  // column id (all D cols identical)
  const int r = m & 3;      // d-component select
  const int el = 16 * wv + 4 * p + r;  // my tail element

  // Stage input row (coalesced float4).
  {
    const float4* src = (const float4*)(data + (size_t)b * T);
    float4* dst = (float4*)xs;
    for (int i = tid; i < T / 4; i += 512) dst[i] = src[i];
  }

  constexpr float L2E = 1.44269504088896f;

  // A-frags: gate g -> rows [128g+16wv, 128g+16wv+16), chunk c -> k in
  // [32c,32c+32). Lane holds A[m][32c+8p+j], j=0..7, pre-scaled by Mk(g).
  v8h a[4][4];
#pragma unroll
  for (int g = 0; g < 4; ++g) {
    const int row = 128 * g + 16 * wv + m;
    const float Mr = (g == 2) ? 2.0f * L2E : -L2E;
    const float* wr = W_hh + (size_t)row * Hdim + 8 * p;
#pragma unroll
    for (int c = 0; c < 4; ++c) {
      float4 v0 = ((const float4*)(wr + 32 * c))[0];
      float4 v1 = ((const float4*)(wr + 32 * c))[1];
      a[g][c] = v8h{(_Float16)(Mr * v0.x), (_Float16)(Mr * v0.y),
                    (_Float16)(Mr * v0.z), (_Float16)(Mr * v0.w),
                    (_Float16)(Mr * v1.x), (_Float16)(Mr * v1.y),
                    (_Float16)(Mr * v1.z), (_Float16)(Mr * v1.w)};
    }
  }

  // Bias seeds (C operand of each gate's a-chain first MFMA) + zero seed
  // for the b-chains (loop-invariant registers, no per-step movs).
  v4f acc_init[4];
#pragma unroll
  for (int g = 0; g < 4; ++g) {
    const float Mr = (g == 2) ? 2.0f * L2E : -L2E;
    const int row = 128 * g + 16 * wv + 4 * p;
    acc_init[g] = v4f{Mr * (b_ih[row + 0] + b_hh[row + 0]),
                      Mr * (b_ih[row + 1] + b_hh[row + 1]),
                      Mr * (b_ih[row + 2] + b_hh[row + 2]),
                      Mr * (b_ih[row + 3] + b_hh[row + 3])};
  }
  const v4f vzero = {0.f, 0.f, 0.f, 0.f};

  // Tail constants: Mk-scaled W_ih for my element, per gate.
  float wih[4];
#pragma unroll
  for (int g = 0; g < 4; ++g) {
    const float Mr = (g == 2) ? 2.0f * L2E : -L2E;
    wih[g] = Mr * W_ih[128 * g + el];
  }

  // c-state pre-scaled by 2*L2E (tanh entry has no mul).
  constexpr float C2 = 2.0f * L2E;
  float cs = C2 * c0[(size_t)b * Hdim + el];
  if (tid < 128) hbuf[0][tid] = (_Float16)h0[(size_t)b * Hdim + tid];
  __syncthreads();

  for (int t0 = 0; t0 < T; t0 += 4) {
    const float4 xv = *(const float4*)&xs[t0];  // 4 steps of x, one read
    const float xts[4] = {xv.x, xv.y, xv.z, xv.w};
#pragma unroll
    for (int u = 0; u < 4; ++u) {
      const int t = t0 + u;
      const _Float16* hb = hbuf[t & 1];
      _Float16* hn = hbuf[(t + 1) & 1];
      // B-frags: h chunk c, lane reads h[32c+8p+j] (16-lane broadcast).
      v8h bq[4];
#pragma unroll
      for (int c = 0; c < 4; ++c) bq[c] = *(const v8h*)(hb + 32 * c + 8 * p);
      const float xt = xts[u];

      // 8 independent 2-deep chains: gate g split into a (c=0,1) and
      // b (c=2,3). Round-robin issue, 8-slot self-spacing. Gate-major
      // order (i_a,i_b,f_a,f_b,g_a,g_b,o_a,o_b) -> gate i's preact is
      // complete ~10/16 through the drain, f at 12/16, g at 14/16.
      v4f da0 = __builtin_amdgcn_mfma_f32_16x16x32_f16(a[0][0], bq[0],
                                                       acc_init[0], 0, 0, 0);
      v4f db0 = __builtin_amdgcn_mfma_f32_16x16x32_f16(a[0][2], bq[2],
                                                       vzero, 0, 0, 0);
      v4f da1 = __builtin_amdgcn_mfma_f32_16x16x32_f16(a[1][0], bq[0],
                                                       acc_init[1], 0, 0, 0);
      v4f db1 = __builtin_amdgcn_mfma_f32_16x16x32_f16(a[1][2], bq[2],
                                                       vzero, 0, 0, 0);
      v4f da2 = __builtin_amdgcn_mfma_f32_16x16x32_f16(a[2][0], bq[0],
                                                       acc_init[2], 0, 0, 0);
      v4f db2 = __builtin_amdgcn_mfma_f32_16x16x32_f16(a[2][2], bq[2],
                                                       vzero, 0, 0, 0);
      v4f da3 = __builtin_amdgcn_mfma_f32_16x16x32_f16(a[3][0], bq[0],
                                                       acc_init[3], 0, 0, 0);
      v4f db3 = __builtin_amdgcn_mfma_f32_16x16x32_f16(a[3][2], bq[2],
                                                       vzero, 0, 0, 0);
      // Round 2.
      da0 = __builtin_amdgcn_mfma_f32_16x16x32_f16(a[0][1], bq[1], da0, 0, 0, 0);
      db0 = __builtin_amdgcn_mfma_f32_16x16x32_f16(a[0][3], bq[3], db0, 0, 0, 0);
      da1 = __builtin_amdgcn_mfma_f32_16x16x32_f16(a[1][1], bq[1], da1, 0, 0, 0);
      db1 = __builtin_amdgcn_mfma_f32_16x16x32_f16(a[1][3], bq[3], db1, 0, 0, 0);
      da2 = __builtin_amdgcn_mfma_f32_16x16x32_f16(a[2][1], bq[1], da2, 0, 0, 0);
      db2 = __builtin_amdgcn_mfma_f32_16x16x32_f16(a[2][3], bq[3], db2, 0, 0, 0);
      da3 = __builtin_amdgcn_mfma_f32_16x16x32_f16(a[3][1], bq[1], da3, 0, 0, 0);
      db3 = __builtin_amdgcn_mfma_f32_16x16x32_f16(a[3][3], bq[3], db3, 0, 0, 0);

      // Tail in gate-retirement order: i finishes first, o last.
      const v4f s0 = da0 + db0;
      const float zi = sel4(s0, r);
      const float yi =
          __builtin_amdgcn_rcpf(1.0f + exp2_fast(fmaf(xt, wih[0], zi)));
      const v4f s1 = da1 + db1;
      const float zf = sel4(s1, r);
      const float yf =
          __builtin_amdgcn_rcpf(1.0f + exp2_fast(fmaf(xt, wih[1], zf)));
      const v4f s2 = da2 + db2;
      const float zg = sel4(s2, r);
      const float ygs = fmaf(
          -2.0f * C2,
          __builtin_amdgcn_rcpf(1.0f + exp2_fast(fmaf(xt, wih[2], zg))), C2);
      cs = fmaf(yf, cs, yi * ygs);  // cs = C2 * c
      const float th =
          fmaf(-2.0f, __builtin_amdgcn_rcpf(1.0f + exp2_fast(cs)), 1.0f);
      const v4f s3 = da3 + db3;
      const float zo = sel4(s3, r);
      const float yo =
          __builtin_amdgcn_rcpf(1.0f + exp2_fast(fmaf(xt, wih[3], zo)));
      const float h = yo * th;

      if (m < 4) hn[el] = (_Float16)h;
      __syncthreads();
    }
  }

  // Final linear: out[b] = h_T . W_out + b_out (wave 0).
  if (tid < 64) {
    const _Float16* hf = hbuf[T & 1];
    float sum =
        (float)hf[tid] * W_out[tid] + (float)hf[tid + 64] * W_out[tid + 64];
#pragma unroll
    for (int off = 32; off > 0; off >>= 1) sum += __shfl_down(sum, off, 64);
    if (tid == 0) out[b] = sum + b_out[0];
  }
}

extern "C" void kernel_launch(void* const* d_in, const int* in_sizes, int n_in,
                              void* d_out, int out_size, void* d_ws,
                              size_t ws_size, hipStream_t stream) {
  const float* data = (const float*)d_in[0];
  const float* h0 = (const float*)d_in[1];
  const float* c0 = (const float*)d_in[2];
  const float* W_ih = (const float*)d_in[3];
  const float* W_hh = (const float*)d_in[4];
  const float* b_ih = (const float*)d_in[5];
  const float* b_hh = (const float*)d_in[6];
  const float* W_out = (const float*)d_in[7];
  const float* b_out = (const float*)d_in[8];
  float* out = (float*)d_out;

  const int B = in_sizes[1] / Hdim;  // 64
  const int T = in_sizes[0] / B;     // 4096

  lstm_mfma<<<B, 512, 0, stream>>>(data, h0, c0, W_ih, W_hh, b_ih, b_hh,
                                   W_out, b_out, out, T);
}